// Round 20
// baseline (61.805 us; speedup 1.0000x reference)
//
#include <hip/hip_runtime.h>

#define B_SZ 2048
#define D_IN 256
#define L_N 48
#define H_N 256
#define O_N 10
#define WROW 303      // D + L - 1
#define LEAF_N 12336  // L*(D+1)
#define KTRI 1176     // 48*49/2 packed lower-tri cols
#define KH2 1224      // KTRI + 48 offs cols
#define KPAD2 1280    // padded K (20 x 64)

using short8 = __attribute__((ext_vector_type(8))) short;
using f32x4  = __attribute__((ext_vector_type(4))) float;

__device__ inline void bf16_split(float v, unsigned short& h, unsigned short& l) {
  unsigned bits = __float_as_uint(v);
  h = (unsigned short)(bits >> 16);
  float hf = __uint_as_float(bits & 0xFFFF0000u);
  float r = v - hf;
  l = (unsigned short)(__float_as_uint(r) >> 16);
}
__device__ inline unsigned short bf16_hi(float v) {
  return (unsigned short)(__float_as_uint(v) >> 16);
}

// ---------------------------------------------------------------------------
// Kernel 0: transpose W for lane-coalesced seq access.
// WtX[d*48+i] = W[i*303+d] (d<256); WtH[k*48+i] = W[i*303+256+k] (k<47).
// W is 58KB -> L2-resident; scatter reads cheap at this size. ~3 us.
// ---------------------------------------------------------------------------
__global__ __launch_bounds__(256) void k_tr(const float* __restrict__ W,
                                            float* __restrict__ WtX,
                                            float* __restrict__ WtH) {
  int t = blockIdx.x * 256 + threadIdx.x;
  if (t < 256 * 48) {
    int d = t / 48, i = t - d * 48;
    WtX[t] = W[i * WROW + d];
  } else if (t < 256 * 48 + 47 * 48) {
    int e = t - 256 * 48;
    int k = e / 48, i = e - k * 48;
    WtH[e] = W[i * WROW + 256 + k];
  }
}

// ---------------------------------------------------------------------------
// seq body: R12-proven structure, but P-loop + whr read the TRANSPOSED W
// (lane-coalesced: 48 consecutive floats per instr instead of 48-line
// scatter). Solve keeps wave-uniform GLOBAL s_loads (SGPR operands).
// ---------------------------------------------------------------------------
__device__ __forceinline__ void seq_wave(int b, int lane,
                                         const float* __restrict__ W,
                                         const float* __restrict__ WtX,
                                         const float* __restrict__ WtH,
                                         const float* __restrict__ x,
                                         const float* __restrict__ bvec,
                                         unsigned short* __restrict__ Ch,
                                         unsigned short* __restrict__ Cl,
                                         float* __restrict__ mask_out) {
  float Preg = 0.f;
  if (lane < 48) {
    const float* xr = x + (size_t)b * D_IN;
    float a0 = 0.f, a1 = 0.f, a2 = 0.f, a3 = 0.f;
#pragma unroll 4
    for (int d = 0; d < 256; d += 4) {
      a0 = fmaf(xr[d + 0], WtX[(d + 0) * 48 + lane], a0);
      a1 = fmaf(xr[d + 1], WtX[(d + 1) * 48 + lane], a1);
      a2 = fmaf(xr[d + 2], WtX[(d + 2) * 48 + lane], a2);
      a3 = fmaf(xr[d + 3], WtX[(d + 3) * 48 + lane], a3);
    }
    Preg = (a0 + a1) + (a2 + a3);
  }

  float whr[47];
#pragma unroll
  for (int k = 0; k < 47; ++k)
    whr[k] = (lane < 48) ? WtH[k * 48 + lane] : 0.f;

  float Pb = Preg + ((lane < 48) ? bvec[lane] : 0.f);

  float accA = 0.f, accB = 0.f;
  float offs_lane = 0.f;
  int d_lane = 0;
#pragma unroll
  for (int i = 0; i < 48; ++i) {
    float z = Pb + accA;
    float u = Preg + accB;
    float a_i = fmaxf(z, 0.f);
    bool dpos = z > 0.f;
    float o_i = dpos ? u : 0.f;
    if (lane == i) {
      d_lane = dpos ? 1 : 0;
      offs_lane = a_i - o_i;
    }
    float ab = __shfl(a_i, i);
    float ob = __shfl(o_i, i);
    if (i < 47) {
      accA += whr[i] * ab;
      accB += whr[i] * ob;
    }
  }
  unsigned long long dmask = __ballot(d_lane);

  float s[48];
  s[0] = ((dmask & 1ULL) && lane == 0) ? 1.f : 0.f;
#pragma unroll
  for (int i = 1; i < 48; ++i) {
    if ((dmask >> i) & 1ULL) {
      const float* wrow = W + i * WROW + 256;  // wave-uniform -> s_load
      float t0 = (lane == i) ? 1.f : 0.f;
      float t1 = 0.f, t2 = 0.f, t3 = 0.f;
      int k = 0;
#pragma unroll
      for (; k + 3 < i; k += 4) {
        t0 += wrow[k + 0] * s[k + 0];
        t1 += wrow[k + 1] * s[k + 1];
        t2 += wrow[k + 2] * s[k + 2];
        t3 += wrow[k + 3] * s[k + 3];
      }
#pragma unroll
      for (; k < i; ++k) t0 += wrow[k] * s[k];
      s[i] = (t0 + t1) + (t2 + t3);
    } else {
      s[i] = 0.f;
    }
  }

  size_t base = (size_t)b * KPAD2;
  if (lane < 48) {
#pragma unroll
    for (int i = 0; i < 48; ++i) {
      if (lane <= i) {
        unsigned short h, l;
        bf16_split(s[i], h, l);
        Ch[base + i * (i + 1) / 2 + lane] = h;
        Cl[base + i * (i + 1) / 2 + lane] = l;
      }
    }
    unsigned short h, l;
    bf16_split(offs_lane, h, l);
    Ch[base + KTRI + lane] = h;
    Cl[base + KTRI + lane] = l;
    mask_out[b * 48 + lane] = d_lane ? 1.f : 0.f;
  }
  for (int e = KH2 + lane; e < KPAD2; e += 64) {
    Ch[base + e] = 0;
    Cl[base + e] = 0;
  }
}

// ---------------------------------------------------------------------------
// Kernel 1 (merged, 704 blocks x 256 thr):
// blocks [0,192): ghat via MFMA (R19-proven): per (i, 64-h tile), K=256 in
//   4 rounds, fp32->bf16 hi/lo inline in staging, 2-term MFMA, tri-skip.
// blocks [192,704): seq, 4 waves, one batch row each.
// ---------------------------------------------------------------------------
#define GLP 72  // ghat LDS row stride (ushorts)
__global__ __launch_bounds__(256) void k1(const float* __restrict__ W,
                                          const float* __restrict__ WtX,
                                          const float* __restrict__ WtH,
                                          const float* __restrict__ Wb0,
                                          const float* __restrict__ x,
                                          const float* __restrict__ bvec,
                                          unsigned short* __restrict__ Gh,
                                          unsigned short* __restrict__ Ch,
                                          unsigned short* __restrict__ Cl,
                                          float* __restrict__ mask_out) {
  const int bid = blockIdx.x;
  const int t = threadIdx.x;
  if (bid < 192) {
    __shared__ unsigned short AhL[64 * GLP], AlL[64 * GLP], BhL[48 * GLP];
    const int i  = bid % 48;
    const int h0 = (bid / 48) * 64;
    const int w = t >> 6;
    const int lane = t & 63;
    const int fr = lane & 15;
    const int fq = lane >> 4;
    const int arow = t >> 4;        // A staging: 16 rows/pass
    const int ac0 = (t & 15) * 4;   // 4 consecutive cols
    f32x4 acc[3] = {};
    for (int it = 0; it < 4; ++it) {
      const int dc = it * 64;
      __syncthreads();
#pragma unroll
      for (int p = 0; p < 4; ++p) {
        int r = arow + p * 16;
        const float* src = Wb0 + (size_t)(h0 + r) * LEAF_N + i * 257 + dc + ac0;
        float v0 = src[0], v1 = src[1], v2 = src[2], v3 = src[3];
        ushort4 hh, ll;
        bf16_split(v0, hh.x, ll.x);
        bf16_split(v1, hh.y, ll.y);
        bf16_split(v2, hh.z, ll.z);
        bf16_split(v3, hh.w, ll.w);
        *(ushort4*)&AhL[r * GLP + ac0] = hh;
        *(ushort4*)&AlL[r * GLP + ac0] = ll;
      }
      for (int e = t; e < 48 * 64; e += 256) {
        int r = e >> 6, c = e & 63;
        BhL[r * GLP + c] = bf16_hi(W[r * WROW + dc + c]);
      }
      __syncthreads();
#pragma unroll
      for (int ks = 0; ks < 2; ++ks) {
        int aoff = (w * 16 + fr) * GLP + fq * 8 + ks * 32;
        short8 ah = *(const short8*)&AhL[aoff];
        short8 al = *(const short8*)&AlL[aoff];
#pragma unroll
        for (int nt = 0; nt < 3; ++nt) {
          if (nt * 16 <= i) {  // tri-skip (uniform branch)
            short8 bh = *(const short8*)&BhL[(nt * 16 + fr) * GLP + fq * 8 + ks * 32];
            acc[nt] = __builtin_amdgcn_mfma_f32_16x16x32_bf16(ah, bh, acc[nt], 0, 0, 0);
            acc[nt] = __builtin_amdgcn_mfma_f32_16x16x32_bf16(al, bh, acc[nt], 0, 0, 0);
          }
        }
      }
    }
    const int tb = i * (i + 1) / 2;
#pragma unroll
    for (int nt = 0; nt < 3; ++nt) {
      int k = nt * 16 + fr;
      if (k <= i) {
#pragma unroll
        for (int r = 0; r < 4; ++r) {
          int m = w * 16 + fq * 4 + r;
          Gh[(size_t)(h0 + m) * KPAD2 + tb + k] = bf16_hi(acc[nt][r]);
        }
      }
    }
    if (t < 64)
      Gh[(size_t)(h0 + t) * KPAD2 + KTRI + i] =
          bf16_hi(Wb0[(size_t)(h0 + t) * LEAF_N + i * 257 + 256]);
    if (i == 0) {
      for (int e = t; e < 64 * (KPAD2 - KH2); e += 256) {
        int r = e / (KPAD2 - KH2), c = e - r * (KPAD2 - KH2);
        Gh[(size_t)(h0 + r) * KPAD2 + KH2 + c] = 0;
      }
    }
    return;
  }
  const int b = (bid - 192) * 4 + (t >> 6);  // batches 0..2047
  seq_wave(b, t & 63, W, WtX, WtH, x, bvec, Ch, Cl, mask_out);
}

// ---------------------------------------------------------------------------
// Kernel 2: big GEMM, 2-term bf16 MFMA: acc = Ah*Bh + Al*Bh.
// 4 waves, LDS-staged, LDSP=88. K=1280 split 4x320. XCD-chunk-swizzled.
// ---------------------------------------------------------------------------
#define LDSP 88
__global__ __launch_bounds__(256) void k_gemm_bf16(
    const unsigned short* __restrict__ Ah, const unsigned short* __restrict__ Al,
    const unsigned short* __restrict__ Bh,
    float* __restrict__ part) {
  int flat = blockIdx.x + 32 * blockIdx.y + 128 * blockIdx.z;  // 0..511
  int id = (flat & 7) * 64 + (flat >> 3);                      // XCD chunks
  const int bz = id & 3, by = (id >> 2) & 3, bx = id >> 4;
  const int m0 = bx * 64;
  const int n0 = by * 64;
  const int k0 = bz * 320;
  float* dst = part + (size_t)bz * ((size_t)B_SZ * H_N);
  __shared__ unsigned short AhL[64 * LDSP], AlL[64 * LDSP];
  __shared__ unsigned short BhL[64 * LDSP];
  const int t = threadIdx.x;
  const int lane = t & 63;
  const int w = t >> 6;
  const int fr = lane & 15;
  const int fq = lane >> 4;
  f32x4 acc[4] = {};
  for (int it = 0; it < 5; ++it) {
    int kb = k0 + it * 64;
#pragma unroll
    for (int j = 0; j < 2; ++j) {
      int c = t + j * 256;
      int row = c >> 3, ko = (c & 7) * 8;
      size_t ga = (size_t)(m0 + row) * KPAD2 + kb + ko;
      size_t gb = (size_t)(n0 + row) * KPAD2 + kb + ko;
      *(short8*)&AhL[row * LDSP + ko] = *(const short8*)&Ah[ga];
      *(short8*)&AlL[row * LDSP + ko] = *(const short8*)&Al[ga];
      *(short8*)&BhL[row * LDSP + ko] = *(const short8*)&Bh[gb];
    }
    __syncthreads();
#pragma unroll
    for (int ks = 0; ks < 2; ++ks) {
      int aoff = (w * 16 + fr) * LDSP + fq * 8 + ks * 32;
      short8 ah = *(const short8*)&AhL[aoff];
      short8 al = *(const short8*)&AlL[aoff];
#pragma unroll
      for (int nt = 0; nt < 4; ++nt) {
        int boff = (nt * 16 + fr) * LDSP + fq * 8 + ks * 32;
        short8 bh = *(const short8*)&BhL[boff];
        acc[nt] = __builtin_amdgcn_mfma_f32_16x16x32_bf16(ah, bh, acc[nt], 0, 0, 0);
        acc[nt] = __builtin_amdgcn_mfma_f32_16x16x32_bf16(al, bh, acc[nt], 0, 0, 0);
      }
    }
    __syncthreads();
  }
  // C layout: col = lane&15, row = (lane>>4)*4 + reg  [m89-verified]
  int mrow = m0 + w * 16 + fq * 4;
#pragma unroll
  for (int nt = 0; nt < 4; ++nt) {
    int ncol = n0 + nt * 16 + fr;
#pragma unroll
    for (int r = 0; r < 4; ++r)
      dst[(size_t)(mrow + r) * H_N + ncol] = acc[nt][r];
  }
}

// ---------------------------------------------------------------------------
// Kernel 3: h1 = relu( relu(sum_z part_z + bb0) @ Wb1^T + bb1 ) via bf16
// MFMA; fused reduce+bias+relu+bf16 in A-staging. BM=64 BN=32, 4 waves.
// ---------------------------------------------------------------------------
#define LDSP2 72
__global__ __launch_bounds__(256) void k_gemm2b(const float* __restrict__ part,
                                                const float* __restrict__ bb0,
                                                const float* __restrict__ Bm,
                                                const float* __restrict__ bias,
                                                float* __restrict__ h1) {
  int flat = blockIdx.x + 32 * blockIdx.y;      // 0..255
  int id = (flat & 7) * 32 + (flat >> 3);       // XCD chunks, x slowest
  const int m0 = (id >> 3) * 64;
  const int n0 = (id & 7) * 32;
  const size_t BH = (size_t)B_SZ * H_N;
  __shared__ unsigned short AtL[64 * LDSP2];
  __shared__ unsigned short BtL[32 * LDSP2];
  const int t = threadIdx.x;
  const int lane = t & 63;
  const int w = t >> 6;
  const int fr = lane & 15;
  const int fq = lane >> 4;
  f32x4 acc[2] = {};
  for (int it = 0; it < 4; ++it) {
    int kb = it * 64;
#pragma unroll
    for (int j = 0; j < 4; ++j) {
      int g = t + j * 256;
      int row = g >> 4, c4 = g & 15;
      size_t base = (size_t)(m0 + row) * H_N + kb + c4 * 4;
      float4 v0 = *(const float4*)&part[base];
      float4 v1 = *(const float4*)&part[base + BH];
      float4 v2 = *(const float4*)&part[base + 2 * BH];
      float4 v3 = *(const float4*)&part[base + 3 * BH];
      float4 bi = *(const float4*)&bb0[kb + c4 * 4];
      ushort4 o;
      o.x = bf16_hi(fmaxf(v0.x + v1.x + v2.x + v3.x + bi.x, 0.f));
      o.y = bf16_hi(fmaxf(v0.y + v1.y + v2.y + v3.y + bi.y, 0.f));
      o.z = bf16_hi(fmaxf(v0.z + v1.z + v2.z + v3.z + bi.z, 0.f));
      o.w = bf16_hi(fmaxf(v0.w + v1.w + v2.w + v3.w + bi.w, 0.f));
      *(ushort4*)&AtL[row * LDSP2 + c4 * 4] = o;
    }
#pragma unroll
    for (int j = 0; j < 2; ++j) {
      int g = t + j * 256;
      int row = g >> 4, c4 = g & 15;
      float4 v = *(const float4*)&Bm[(size_t)(n0 + row) * H_N + kb + c4 * 4];
      ushort4 o;
      o.x = bf16_hi(v.x); o.y = bf16_hi(v.y);
      o.z = bf16_hi(v.z); o.w = bf16_hi(v.w);
      *(ushort4*)&BtL[row * LDSP2 + c4 * 4] = o;
    }
    __syncthreads();
#pragma unroll
    for (int ks = 0; ks < 2; ++ks) {
      short8 a8 = *(const short8*)&AtL[(w * 16 + fr) * LDSP2 + fq * 8 + ks * 32];
#pragma unroll
      for (int nt = 0; nt < 2; ++nt) {
        short8 b8 =
            *(const short8*)&BtL[(nt * 16 + fr) * LDSP2 + fq * 8 + ks * 32];
        acc[nt] = __builtin_amdgcn_mfma_f32_16x16x32_bf16(a8, b8, acc[nt], 0, 0, 0);
      }
    }
    __syncthreads();
  }
  int mrow = m0 + w * 16 + fq * 4;
#pragma unroll
  for (int nt = 0; nt < 2; ++nt) {
    int ncol = n0 + nt * 16 + fr;
    float bs = bias[ncol];
#pragma unroll
    for (int r = 0; r < 4; ++r)
      h1[(size_t)(mrow + r) * H_N + ncol] = fmaxf(acc[nt][r] + bs, 0.f);
  }
}

// ---------------------------------------------------------------------------
// Kernel 4: out[b,:] = h1[b,:] @ Wout^T + bout. One wave per batch row.
// ---------------------------------------------------------------------------
__global__ __launch_bounds__(256) void k_out(const float* __restrict__ h1,
                                             const float* __restrict__ Wout,
                                             const float* __restrict__ bout,
                                             float* __restrict__ out) {
  int w = threadIdx.x >> 6, lane = threadIdx.x & 63;
  int b = blockIdx.x * 4 + w;
  const float* hr = h1 + (size_t)b * H_N;
  float h[4];
#pragma unroll
  for (int j = 0; j < 4; ++j) h[j] = hr[lane + 64 * j];
  float acc[10];
#pragma unroll
  for (int o = 0; o < 10; ++o) {
    float s = 0.f;
#pragma unroll
    for (int j = 0; j < 4; ++j) s += h[j] * Wout[o * H_N + lane + 64 * j];
#pragma unroll
    for (int m = 32; m >= 1; m >>= 1) s += __shfl_xor(s, m);
    acc[o] = s;
  }
  if (lane == 0) {
#pragma unroll
    for (int o = 0; o < 10; ++o) out[(size_t)b * O_N + o] = acc[o] + bout[o];
  }
}

// ---------------------------------------------------------------------------
extern "C" void kernel_launch(void* const* d_in, const int* in_sizes, int n_in,
                              void* d_out, int out_size, void* d_ws,
                              size_t ws_size, hipStream_t stream) {
  (void)in_sizes; (void)n_in; (void)out_size; (void)ws_size;
  const float* x    = (const float*)d_in[0];
  const float* W    = (const float*)d_in[1];
  const float* bvec = (const float*)d_in[2];
  const float* Wb0  = (const float*)d_in[3];
  const float* bb0  = (const float*)d_in[4];
  const float* Wb1  = (const float*)d_in[5];
  const float* bb1  = (const float*)d_in[6];
  const float* Wout = (const float*)d_in[7];
  const float* bout = (const float*)d_in[8];

  float* out   = (float*)d_out;     // B*10
  float* masks = out + B_SZ * O_N;  // B*48

  char* wsb = (char*)d_ws;
  unsigned short* Ch = (unsigned short*)wsb;                // B*KPAD2 us
  unsigned short* Cl = Ch + (size_t)B_SZ * KPAD2;
  unsigned short* Gh = Cl + (size_t)B_SZ * KPAD2;           // H*KPAD2 us
  float* part = (float*)(Gh + (size_t)H_N * KPAD2);         // 4*B*H f32
  float* h1 = part + 4 * (size_t)B_SZ * H_N;                // B*H f32
  float* WtX = h1 + (size_t)B_SZ * H_N;                     // 256*48 f32
  float* WtH = WtX + 256 * 48;                              // 47*48 f32
  // total ~22 MB

  k_tr<<<dim3(57), 256, 0, stream>>>(W, WtX, WtH);
  k1<<<dim3(704), 256, 0, stream>>>(W, WtX, WtH, Wb0, x, bvec, Gh, Ch, Cl,
                                    masks);
  k_gemm_bf16<<<dim3(32, 4, 4), 256, 0, stream>>>(Ch, Cl, Gh, part);
  k_gemm2b<<<dim3(32, 8), 256, 0, stream>>>(part, bb0, Wb1, bb1, h1);
  k_out<<<dim3(512), 256, 0, stream>>>(h1, Wout, bout, out);
}

// Round 21
// 60.202 us; speedup vs baseline: 1.0266x; 1.0266x over previous
//
#include <hip/hip_runtime.h>

#define B_SZ 2048
#define D_IN 256
#define L_N 48
#define H_N 256
#define O_N 10
#define WROW 303      // D + L - 1
#define LEAF_N 12336  // L*(D+1)
#define KTRI 1176     // 48*49/2 packed lower-tri cols
#define KH2 1224      // KTRI + 48 offs cols
#define KPAD2 1280    // padded K (20 x 64)

using short8 = __attribute__((ext_vector_type(8))) short;
using f32x4  = __attribute__((ext_vector_type(4))) float;

__device__ inline void bf16_split(float v, unsigned short& h, unsigned short& l) {
  unsigned bits = __float_as_uint(v);
  h = (unsigned short)(bits >> 16);
  float hf = __uint_as_float(bits & 0xFFFF0000u);
  float r = v - hf;
  l = (unsigned short)(__float_as_uint(r) >> 16);
}
__device__ inline unsigned short bf16_hi(float v) {
  return (unsigned short)(__float_as_uint(v) >> 16);
}

// ---------------------------------------------------------------------------
// seq body, FUSED: solve row i is computed inside the recurrence loop, in the
// shadow of the shfl broadcast latency. d_i comes free as (ab > 0), so the
// solve has NO data-dependent branch -> wave-uniform s_loads pipeline ahead.
// ---------------------------------------------------------------------------
__device__ __forceinline__ void seq_wave(int b, int lane,
                                         const float* __restrict__ W,
                                         const float* __restrict__ x,
                                         const float* __restrict__ bvec,
                                         unsigned short* __restrict__ Ch,
                                         unsigned short* __restrict__ Cl,
                                         float* __restrict__ mask_out) {
  float Preg = 0.f;
  if (lane < 48) {
    const float* xr = x + (size_t)b * D_IN;
    const float* wr = W + lane * WROW;
    float a0 = 0.f, a1 = 0.f, a2 = 0.f, a3 = 0.f;
#pragma unroll 4
    for (int d = 0; d < 256; d += 4) {
      a0 = fmaf(xr[d + 0], wr[d + 0], a0);
      a1 = fmaf(xr[d + 1], wr[d + 1], a1);
      a2 = fmaf(xr[d + 2], wr[d + 2], a2);
      a3 = fmaf(xr[d + 3], wr[d + 3], a3);
    }
    Preg = (a0 + a1) + (a2 + a3);
  }

  float whr[47];
#pragma unroll
  for (int k = 0; k < 47; ++k)
    whr[k] = (lane < 48) ? W[lane * WROW + 256 + k] : 0.f;

  float Pb = Preg + ((lane < 48) ? bvec[lane] : 0.f);

  float s[48];
  float accA = 0.f, accB = 0.f;
  float offs_lane = 0.f;
  int d_lane = 0;
#pragma unroll
  for (int i = 0; i < 48; ++i) {
    float z = Pb + accA;
    float u = Preg + accB;
    float a_i = fmaxf(z, 0.f);
    bool dpos = z > 0.f;
    float o_i = dpos ? u : 0.f;
    if (lane == i) {
      d_lane = dpos ? 1 : 0;
      offs_lane = a_i - o_i;
    }
    float ab = __shfl(a_i, i);   // broadcast a_i; also encodes d_i = (ab>0)
    float ob = __shfl(o_i, i);
    // solve row i, overlapped with the shfl latency; branchless:
    // s[i] = d_i * (sum_{k<i} wh_i[k] s[k] + (lane==i))
    {
      const float* wrow = W + i * WROW + 256;  // wave-uniform -> s_load
      float t0 = (lane == i) ? 1.f : 0.f;
      float t1 = 0.f, t2 = 0.f, t3 = 0.f;
      int k = 0;
#pragma unroll
      for (; k + 3 < i; k += 4) {
        t0 = fmaf(wrow[k + 0], s[k + 0], t0);
        t1 = fmaf(wrow[k + 1], s[k + 1], t1);
        t2 = fmaf(wrow[k + 2], s[k + 2], t2);
        t3 = fmaf(wrow[k + 3], s[k + 3], t3);
      }
#pragma unroll
      for (; k < i; ++k) t0 = fmaf(wrow[k], s[k], t0);
      s[i] = (ab > 0.f) ? ((t0 + t1) + (t2 + t3)) : 0.f;
    }
    if (i < 47) {
      accA += whr[i] * ab;
      accB += whr[i] * ob;
    }
  }
  unsigned long long dmask = __ballot(d_lane);

  size_t base = (size_t)b * KPAD2;
  if (lane < 48) {
#pragma unroll
    for (int i = 0; i < 48; ++i) {
      if (lane <= i) {
        unsigned short h, l;
        bf16_split(s[i], h, l);
        Ch[base + i * (i + 1) / 2 + lane] = h;
        Cl[base + i * (i + 1) / 2 + lane] = l;
      }
    }
    unsigned short h, l;
    bf16_split(offs_lane, h, l);
    Ch[base + KTRI + lane] = h;
    Cl[base + KTRI + lane] = l;
    mask_out[b * 48 + lane] = d_lane ? 1.f : 0.f;
  }
  for (int e = KH2 + lane; e < KPAD2; e += 64) {
    Ch[base + e] = 0;
    Cl[base + e] = 0;
  }
}

// ---------------------------------------------------------------------------
// Kernel 1 (merged, 704 blocks x 256 thr):
// blocks [0,192): ghat via MFMA (R19-proven): per (i, 64-h tile), K=256 in
//   4 rounds, fp32->bf16 hi/lo inline in staging, 2-term MFMA, tri-skip.
// blocks [192,704): seq, 4 waves, one batch row each (fused form).
// ---------------------------------------------------------------------------
#define GLP 72  // ghat LDS row stride (ushorts)
__global__ __launch_bounds__(256) void k1(const float* __restrict__ W,
                                          const float* __restrict__ Wb0,
                                          const float* __restrict__ x,
                                          const float* __restrict__ bvec,
                                          unsigned short* __restrict__ Gh,
                                          unsigned short* __restrict__ Ch,
                                          unsigned short* __restrict__ Cl,
                                          float* __restrict__ mask_out) {
  const int bid = blockIdx.x;
  const int t = threadIdx.x;
  if (bid < 192) {
    __shared__ unsigned short AhL[64 * GLP], AlL[64 * GLP], BhL[48 * GLP];
    const int i  = bid % 48;
    const int h0 = (bid / 48) * 64;
    const int w = t >> 6;
    const int lane = t & 63;
    const int fr = lane & 15;
    const int fq = lane >> 4;
    const int arow = t >> 4;        // A staging: 16 rows/pass
    const int ac0 = (t & 15) * 4;   // 4 consecutive cols
    f32x4 acc[3] = {};
    for (int it = 0; it < 4; ++it) {
      const int dc = it * 64;
      __syncthreads();
#pragma unroll
      for (int p = 0; p < 4; ++p) {
        int r = arow + p * 16;
        const float* src = Wb0 + (size_t)(h0 + r) * LEAF_N + i * 257 + dc + ac0;
        float v0 = src[0], v1 = src[1], v2 = src[2], v3 = src[3];
        ushort4 hh, ll;
        bf16_split(v0, hh.x, ll.x);
        bf16_split(v1, hh.y, ll.y);
        bf16_split(v2, hh.z, ll.z);
        bf16_split(v3, hh.w, ll.w);
        *(ushort4*)&AhL[r * GLP + ac0] = hh;
        *(ushort4*)&AlL[r * GLP + ac0] = ll;
      }
      for (int e = t; e < 48 * 64; e += 256) {
        int r = e >> 6, c = e & 63;
        BhL[r * GLP + c] = bf16_hi(W[r * WROW + dc + c]);
      }
      __syncthreads();
#pragma unroll
      for (int ks = 0; ks < 2; ++ks) {
        int aoff = (w * 16 + fr) * GLP + fq * 8 + ks * 32;
        short8 ah = *(const short8*)&AhL[aoff];
        short8 al = *(const short8*)&AlL[aoff];
#pragma unroll
        for (int nt = 0; nt < 3; ++nt) {
          if (nt * 16 <= i) {  // tri-skip (uniform branch)
            short8 bh = *(const short8*)&BhL[(nt * 16 + fr) * GLP + fq * 8 + ks * 32];
            acc[nt] = __builtin_amdgcn_mfma_f32_16x16x32_bf16(ah, bh, acc[nt], 0, 0, 0);
            acc[nt] = __builtin_amdgcn_mfma_f32_16x16x32_bf16(al, bh, acc[nt], 0, 0, 0);
          }
        }
      }
    }
    const int tb = i * (i + 1) / 2;
#pragma unroll
    for (int nt = 0; nt < 3; ++nt) {
      int k = nt * 16 + fr;
      if (k <= i) {
#pragma unroll
        for (int r = 0; r < 4; ++r) {
          int m = w * 16 + fq * 4 + r;
          Gh[(size_t)(h0 + m) * KPAD2 + tb + k] = bf16_hi(acc[nt][r]);
        }
      }
    }
    if (t < 64)
      Gh[(size_t)(h0 + t) * KPAD2 + KTRI + i] =
          bf16_hi(Wb0[(size_t)(h0 + t) * LEAF_N + i * 257 + 256]);
    if (i == 0) {
      for (int e = t; e < 64 * (KPAD2 - KH2); e += 256) {
        int r = e / (KPAD2 - KH2), c = e - r * (KPAD2 - KH2);
        Gh[(size_t)(h0 + r) * KPAD2 + KH2 + c] = 0;
      }
    }
    return;
  }
  const int b = (bid - 192) * 4 + (t >> 6);  // batches 0..2047
  seq_wave(b, t & 63, W, x, bvec, Ch, Cl, mask_out);
}

// ---------------------------------------------------------------------------
// Kernel 2: big GEMM, 2-term bf16 MFMA: acc = Ah*Bh + Al*Bh.
// 4 waves, LDS-staged, LDSP=88. K=1280 split 4x320. XCD-chunk-swizzled.
// ---------------------------------------------------------------------------
#define LDSP 88
__global__ __launch_bounds__(256) void k_gemm_bf16(
    const unsigned short* __restrict__ Ah, const unsigned short* __restrict__ Al,
    const unsigned short* __restrict__ Bh,
    float* __restrict__ part) {
  int flat = blockIdx.x + 32 * blockIdx.y + 128 * blockIdx.z;  // 0..511
  int id = (flat & 7) * 64 + (flat >> 3);                      // XCD chunks
  const int bz = id & 3, by = (id >> 2) & 3, bx = id >> 4;
  const int m0 = bx * 64;
  const int n0 = by * 64;
  const int k0 = bz * 320;
  float* dst = part + (size_t)bz * ((size_t)B_SZ * H_N);
  __shared__ unsigned short AhL[64 * LDSP], AlL[64 * LDSP];
  __shared__ unsigned short BhL[64 * LDSP];
  const int t = threadIdx.x;
  const int lane = t & 63;
  const int w = t >> 6;
  const int fr = lane & 15;
  const int fq = lane >> 4;
  f32x4 acc[4] = {};
  for (int it = 0; it < 5; ++it) {
    int kb = k0 + it * 64;
#pragma unroll
    for (int j = 0; j < 2; ++j) {
      int c = t + j * 256;
      int row = c >> 3, ko = (c & 7) * 8;
      size_t ga = (size_t)(m0 + row) * KPAD2 + kb + ko;
      size_t gb = (size_t)(n0 + row) * KPAD2 + kb + ko;
      *(short8*)&AhL[row * LDSP + ko] = *(const short8*)&Ah[ga];
      *(short8*)&AlL[row * LDSP + ko] = *(const short8*)&Al[ga];
      *(short8*)&BhL[row * LDSP + ko] = *(const short8*)&Bh[gb];
    }
    __syncthreads();
#pragma unroll
    for (int ks = 0; ks < 2; ++ks) {
      int aoff = (w * 16 + fr) * LDSP + fq * 8 + ks * 32;
      short8 ah = *(const short8*)&AhL[aoff];
      short8 al = *(const short8*)&AlL[aoff];
#pragma unroll
      for (int nt = 0; nt < 4; ++nt) {
        int boff = (nt * 16 + fr) * LDSP + fq * 8 + ks * 32;
        short8 bh = *(const short8*)&BhL[boff];
        acc[nt] = __builtin_amdgcn_mfma_f32_16x16x32_bf16(ah, bh, acc[nt], 0, 0, 0);
        acc[nt] = __builtin_amdgcn_mfma_f32_16x16x32_bf16(al, bh, acc[nt], 0, 0, 0);
      }
    }
    __syncthreads();
  }
  // C layout: col = lane&15, row = (lane>>4)*4 + reg  [m89-verified]
  int mrow = m0 + w * 16 + fq * 4;
#pragma unroll
  for (int nt = 0; nt < 4; ++nt) {
    int ncol = n0 + nt * 16 + fr;
#pragma unroll
    for (int r = 0; r < 4; ++r)
      dst[(size_t)(mrow + r) * H_N + ncol] = acc[nt][r];
  }
}

// ---------------------------------------------------------------------------
// Kernel 3: h1 = relu( relu(sum_z part_z + bb0) @ Wb1^T + bb1 ) via bf16
// MFMA; fused reduce+bias+relu+bf16 in A-staging. BM=64 BN=32, 4 waves.
// ---------------------------------------------------------------------------
#define LDSP2 72
__global__ __launch_bounds__(256) void k_gemm2b(const float* __restrict__ part,
                                                const float* __restrict__ bb0,
                                                const float* __restrict__ Bm,
                                                const float* __restrict__ bias,
                                                float* __restrict__ h1) {
  int flat = blockIdx.x + 32 * blockIdx.y;      // 0..255
  int id = (flat & 7) * 32 + (flat >> 3);       // XCD chunks, x slowest
  const int m0 = (id >> 3) * 64;
  const int n0 = (id & 7) * 32;
  const size_t BH = (size_t)B_SZ * H_N;
  __shared__ unsigned short AtL[64 * LDSP2];
  __shared__ unsigned short BtL[32 * LDSP2];
  const int t = threadIdx.x;
  const int lane = t & 63;
  const int w = t >> 6;
  const int fr = lane & 15;
  const int fq = lane >> 4;
  f32x4 acc[2] = {};
  for (int it = 0; it < 4; ++it) {
    int kb = it * 64;
#pragma unroll
    for (int j = 0; j < 4; ++j) {
      int g = t + j * 256;
      int row = g >> 4, c4 = g & 15;
      size_t base = (size_t)(m0 + row) * H_N + kb + c4 * 4;
      float4 v0 = *(const float4*)&part[base];
      float4 v1 = *(const float4*)&part[base + BH];
      float4 v2 = *(const float4*)&part[base + 2 * BH];
      float4 v3 = *(const float4*)&part[base + 3 * BH];
      float4 bi = *(const float4*)&bb0[kb + c4 * 4];
      ushort4 o;
      o.x = bf16_hi(fmaxf(v0.x + v1.x + v2.x + v3.x + bi.x, 0.f));
      o.y = bf16_hi(fmaxf(v0.y + v1.y + v2.y + v3.y + bi.y, 0.f));
      o.z = bf16_hi(fmaxf(v0.z + v1.z + v2.z + v3.z + bi.z, 0.f));
      o.w = bf16_hi(fmaxf(v0.w + v1.w + v2.w + v3.w + bi.w, 0.f));
      *(ushort4*)&AtL[row * LDSP2 + c4 * 4] = o;
    }
#pragma unroll
    for (int j = 0; j < 2; ++j) {
      int g = t + j * 256;
      int row = g >> 4, c4 = g & 15;
      float4 v = *(const float4*)&Bm[(size_t)(n0 + row) * H_N + kb + c4 * 4];
      ushort4 o;
      o.x = bf16_hi(v.x); o.y = bf16_hi(v.y);
      o.z = bf16_hi(v.z); o.w = bf16_hi(v.w);
      *(ushort4*)&BtL[row * LDSP2 + c4 * 4] = o;
    }
    __syncthreads();
#pragma unroll
    for (int ks = 0; ks < 2; ++ks) {
      short8 a8 = *(const short8*)&AtL[(w * 16 + fr) * LDSP2 + fq * 8 + ks * 32];
#pragma unroll
      for (int nt = 0; nt < 2; ++nt) {
        short8 b8 =
            *(const short8*)&BtL[(nt * 16 + fr) * LDSP2 + fq * 8 + ks * 32];
        acc[nt] = __builtin_amdgcn_mfma_f32_16x16x32_bf16(a8, b8, acc[nt], 0, 0, 0);
      }
    }
    __syncthreads();
  }
  int mrow = m0 + w * 16 + fq * 4;
#pragma unroll
  for (int nt = 0; nt < 2; ++nt) {
    int ncol = n0 + nt * 16 + fr;
    float bs = bias[ncol];
#pragma unroll
    for (int r = 0; r < 4; ++r)
      h1[(size_t)(mrow + r) * H_N + ncol] = fmaxf(acc[nt][r] + bs, 0.f);
  }
}

// ---------------------------------------------------------------------------
// Kernel 4: out[b,:] = h1[b,:] @ Wout^T + bout. One wave per batch row.
// ---------------------------------------------------------------------------
__global__ __launch_bounds__(256) void k_out(const float* __restrict__ h1,
                                             const float* __restrict__ Wout,
                                             const float* __restrict__ bout,
                                             float* __restrict__ out) {
  int w = threadIdx.x >> 6, lane = threadIdx.x & 63;
  int b = blockIdx.x * 4 + w;
  const float* hr = h1 + (size_t)b * H_N;
  float h[4];
#pragma unroll
  for (int j = 0; j < 4; ++j) h[j] = hr[lane + 64 * j];
  float acc[10];
#pragma unroll
  for (int o = 0; o < 10; ++o) {
    float s = 0.f;
#pragma unroll
    for (int j = 0; j < 4; ++j) s += h[j] * Wout[o * H_N + lane + 64 * j];
#pragma unroll
    for (int m = 32; m >= 1; m >>= 1) s += __shfl_xor(s, m);
    acc[o] = s;
  }
  if (lane == 0) {
#pragma unroll
    for (int o = 0; o < 10; ++o) out[(size_t)b * O_N + o] = acc[o] + bout[o];
  }
}

// ---------------------------------------------------------------------------
extern "C" void kernel_launch(void* const* d_in, const int* in_sizes, int n_in,
                              void* d_out, int out_size, void* d_ws,
                              size_t ws_size, hipStream_t stream) {
  (void)in_sizes; (void)n_in; (void)out_size; (void)ws_size;
  const float* x    = (const float*)d_in[0];
  const float* W    = (const float*)d_in[1];
  const float* bvec = (const float*)d_in[2];
  const float* Wb0  = (const float*)d_in[3];
  const float* bb0  = (const float*)d_in[4];
  const float* Wb1  = (const float*)d_in[5];
  const float* bb1  = (const float*)d_in[6];
  const float* Wout = (const float*)d_in[7];
  const float* bout = (const float*)d_in[8];

  float* out   = (float*)d_out;     // B*10
  float* masks = out + B_SZ * O_N;  // B*48

  char* wsb = (char*)d_ws;
  unsigned short* Ch = (unsigned short*)wsb;                // B*KPAD2 us
  unsigned short* Cl = Ch + (size_t)B_SZ * KPAD2;
  unsigned short* Gh = Cl + (size_t)B_SZ * KPAD2;           // H*KPAD2 us
  float* part = (float*)(Gh + (size_t)H_N * KPAD2);         // 4*B*H f32
  float* h1 = part + 4 * (size_t)B_SZ * H_N;                // B*H f32
  // total ~22 MB

  k1<<<dim3(704), 256, 0, stream>>>(W, Wb0, x, bvec, Gh, Ch, Cl, masks);
  k_gemm_bf16<<<dim3(32, 4, 4), 256, 0, stream>>>(Ch, Cl, Gh, part);
  k_gemm2b<<<dim3(32, 8), 256, 0, stream>>>(part, bb0, Wb1, bb1, h1);
  k_out<<<dim3(512), 256, 0, stream>>>(h1, Wout, bout, out);
}

// Round 22
// 58.325 us; speedup vs baseline: 1.0597x; 1.0322x over previous
//
#include <hip/hip_runtime.h>

#define B_SZ 2048
#define D_IN 256
#define L_N 48
#define H_N 256
#define O_N 10
#define WROW 303      // D + L - 1
#define LEAF_N 12336  // L*(D+1)
#define KTRI 1176     // 48*49/2 packed lower-tri cols
#define KH2 1224      // KTRI + 48 offs cols
#define KPAD2 1280    // padded K (20 x 64)

using short8 = __attribute__((ext_vector_type(8))) short;
using f32x4  = __attribute__((ext_vector_type(4))) float;

__device__ inline void bf16_split(float v, unsigned short& h, unsigned short& l) {
  unsigned bits = __float_as_uint(v);
  h = (unsigned short)(bits >> 16);
  float hf = __uint_as_float(bits & 0xFFFF0000u);
  float r = v - hf;
  l = (unsigned short)(__float_as_uint(r) >> 16);
}
__device__ inline unsigned short bf16_hi(float v) {
  return (unsigned short)(__float_as_uint(v) >> 16);
}
// broadcast lane i's value via v_readlane (SALU, ~10cyc) -- i must be a
// compile-time constant (unrolled loop). Avoids ds_bpermute (~120cyc).
__device__ __forceinline__ float lane_bcast(float v, int i) {
  return __uint_as_float(__builtin_amdgcn_readlane(__float_as_uint(v), i));
}

// ---------------------------------------------------------------------------
// seq body, FUSED + readlane broadcasts: the 48-step recurrence chain uses
// SALU v_readlane instead of ds_bpermute -> ~10x lower chain latency, no DS
// pipe contention. Solve row i overlaps the chain; gating (ab>0) is scalar.
// ---------------------------------------------------------------------------
__device__ __forceinline__ void seq_wave(int b, int lane,
                                         const float* __restrict__ W,
                                         const float* __restrict__ x,
                                         const float* __restrict__ bvec,
                                         unsigned short* __restrict__ Ch,
                                         unsigned short* __restrict__ Cl,
                                         float* __restrict__ mask_out) {
  float Preg = 0.f;
  if (lane < 48) {
    const float* xr = x + (size_t)b * D_IN;
    const float* wr = W + lane * WROW;
    float a0 = 0.f, a1 = 0.f, a2 = 0.f, a3 = 0.f;
#pragma unroll 4
    for (int d = 0; d < 256; d += 4) {
      a0 = fmaf(xr[d + 0], wr[d + 0], a0);
      a1 = fmaf(xr[d + 1], wr[d + 1], a1);
      a2 = fmaf(xr[d + 2], wr[d + 2], a2);
      a3 = fmaf(xr[d + 3], wr[d + 3], a3);
    }
    Preg = (a0 + a1) + (a2 + a3);
  }

  float whr[47];
#pragma unroll
  for (int k = 0; k < 47; ++k)
    whr[k] = (lane < 48) ? W[lane * WROW + 256 + k] : 0.f;

  float Pb = Preg + ((lane < 48) ? bvec[lane] : 0.f);

  float s[48];
  float accA = 0.f, accB = 0.f;
  float offs_lane = 0.f;
  int d_lane = 0;
#pragma unroll
  for (int i = 0; i < 48; ++i) {
    float z = Pb + accA;
    float u = Preg + accB;
    float a_i = fmaxf(z, 0.f);
    bool dpos = z > 0.f;
    float o_i = dpos ? u : 0.f;
    if (lane == i) {
      d_lane = dpos ? 1 : 0;
      offs_lane = a_i - o_i;
    }
    float ab = lane_bcast(a_i, i);  // SALU broadcast; d_i = (ab > 0)
    float ob = lane_bcast(o_i, i);
    // solve row i, overlapped with the chain; branchless:
    // s[i] = d_i * (sum_{k<i} wh_i[k] s[k] + (lane==i))
    {
      const float* wrow = W + i * WROW + 256;  // wave-uniform -> s_load
      float t0 = (lane == i) ? 1.f : 0.f;
      float t1 = 0.f, t2 = 0.f, t3 = 0.f;
      int k = 0;
#pragma unroll
      for (; k + 3 < i; k += 4) {
        t0 = fmaf(wrow[k + 0], s[k + 0], t0);
        t1 = fmaf(wrow[k + 1], s[k + 1], t1);
        t2 = fmaf(wrow[k + 2], s[k + 2], t2);
        t3 = fmaf(wrow[k + 3], s[k + 3], t3);
      }
#pragma unroll
      for (; k < i; ++k) t0 = fmaf(wrow[k], s[k], t0);
      s[i] = (ab > 0.f) ? ((t0 + t1) + (t2 + t3)) : 0.f;
    }
    if (i < 47) {
      accA += whr[i] * ab;
      accB += whr[i] * ob;
    }
  }
  unsigned long long dmask = __ballot(d_lane);

  size_t base = (size_t)b * KPAD2;
  if (lane < 48) {
#pragma unroll
    for (int i = 0; i < 48; ++i) {
      if (lane <= i) {
        unsigned short h, l;
        bf16_split(s[i], h, l);
        Ch[base + i * (i + 1) / 2 + lane] = h;
        Cl[base + i * (i + 1) / 2 + lane] = l;
      }
    }
    unsigned short h, l;
    bf16_split(offs_lane, h, l);
    Ch[base + KTRI + lane] = h;
    Cl[base + KTRI + lane] = l;
    mask_out[b * 48 + lane] = d_lane ? 1.f : 0.f;
  }
  for (int e = KH2 + lane; e < KPAD2; e += 64) {
    Ch[base + e] = 0;
    Cl[base + e] = 0;
  }
}

// ---------------------------------------------------------------------------
// Kernel 1 (merged, 704 blocks x 256 thr):
// blocks [0,192): ghat via MFMA (R19-proven): per (i, 64-h tile), K=256 in
//   4 rounds, fp32->bf16 hi/lo inline in staging, 2-term MFMA, tri-skip.
// blocks [192,704): seq, 4 waves, one batch row each (fused form).
// ---------------------------------------------------------------------------
#define GLP 72  // ghat LDS row stride (ushorts)
__global__ __launch_bounds__(256) void k1(const float* __restrict__ W,
                                          const float* __restrict__ Wb0,
                                          const float* __restrict__ x,
                                          const float* __restrict__ bvec,
                                          unsigned short* __restrict__ Gh,
                                          unsigned short* __restrict__ Ch,
                                          unsigned short* __restrict__ Cl,
                                          float* __restrict__ mask_out) {
  const int bid = blockIdx.x;
  const int t = threadIdx.x;
  if (bid < 192) {
    __shared__ unsigned short AhL[64 * GLP], AlL[64 * GLP], BhL[48 * GLP];
    const int i  = bid % 48;
    const int h0 = (bid / 48) * 64;
    const int w = t >> 6;
    const int lane = t & 63;
    const int fr = lane & 15;
    const int fq = lane >> 4;
    const int arow = t >> 4;        // A staging: 16 rows/pass
    const int ac0 = (t & 15) * 4;   // 4 consecutive cols
    f32x4 acc[3] = {};
    for (int it = 0; it < 4; ++it) {
      const int dc = it * 64;
      __syncthreads();
#pragma unroll
      for (int p = 0; p < 4; ++p) {
        int r = arow + p * 16;
        const float* src = Wb0 + (size_t)(h0 + r) * LEAF_N + i * 257 + dc + ac0;
        float v0 = src[0], v1 = src[1], v2 = src[2], v3 = src[3];
        ushort4 hh, ll;
        bf16_split(v0, hh.x, ll.x);
        bf16_split(v1, hh.y, ll.y);
        bf16_split(v2, hh.z, ll.z);
        bf16_split(v3, hh.w, ll.w);
        *(ushort4*)&AhL[r * GLP + ac0] = hh;
        *(ushort4*)&AlL[r * GLP + ac0] = ll;
      }
      for (int e = t; e < 48 * 64; e += 256) {
        int r = e >> 6, c = e & 63;
        BhL[r * GLP + c] = bf16_hi(W[r * WROW + dc + c]);
      }
      __syncthreads();
#pragma unroll
      for (int ks = 0; ks < 2; ++ks) {
        int aoff = (w * 16 + fr) * GLP + fq * 8 + ks * 32;
        short8 ah = *(const short8*)&AhL[aoff];
        short8 al = *(const short8*)&AlL[aoff];
#pragma unroll
        for (int nt = 0; nt < 3; ++nt) {
          if (nt * 16 <= i) {  // tri-skip (uniform branch)
            short8 bh = *(const short8*)&BhL[(nt * 16 + fr) * GLP + fq * 8 + ks * 32];
            acc[nt] = __builtin_amdgcn_mfma_f32_16x16x32_bf16(ah, bh, acc[nt], 0, 0, 0);
            acc[nt] = __builtin_amdgcn_mfma_f32_16x16x32_bf16(al, bh, acc[nt], 0, 0, 0);
          }
        }
      }
    }
    const int tb = i * (i + 1) / 2;
#pragma unroll
    for (int nt = 0; nt < 3; ++nt) {
      int k = nt * 16 + fr;
      if (k <= i) {
#pragma unroll
        for (int r = 0; r < 4; ++r) {
          int m = w * 16 + fq * 4 + r;
          Gh[(size_t)(h0 + m) * KPAD2 + tb + k] = bf16_hi(acc[nt][r]);
        }
      }
    }
    if (t < 64)
      Gh[(size_t)(h0 + t) * KPAD2 + KTRI + i] =
          bf16_hi(Wb0[(size_t)(h0 + t) * LEAF_N + i * 257 + 256]);
    if (i == 0) {
      for (int e = t; e < 64 * (KPAD2 - KH2); e += 256) {
        int r = e / (KPAD2 - KH2), c = e - r * (KPAD2 - KH2);
        Gh[(size_t)(h0 + r) * KPAD2 + KH2 + c] = 0;
      }
    }
    return;
  }
  const int b = (bid - 192) * 4 + (t >> 6);  // batches 0..2047
  seq_wave(b, t & 63, W, x, bvec, Ch, Cl, mask_out);
}

// ---------------------------------------------------------------------------
// Kernel 2: big GEMM, 2-term bf16 MFMA: acc = Ah*Bh + Al*Bh.
// 4 waves, LDS-staged, LDSP=88. K=1280 split 4x320. XCD-chunk-swizzled.
// ---------------------------------------------------------------------------
#define LDSP 88
__global__ __launch_bounds__(256) void k_gemm_bf16(
    const unsigned short* __restrict__ Ah, const unsigned short* __restrict__ Al,
    const unsigned short* __restrict__ Bh,
    float* __restrict__ part) {
  int flat = blockIdx.x + 32 * blockIdx.y + 128 * blockIdx.z;  // 0..511
  int id = (flat & 7) * 64 + (flat >> 3);                      // XCD chunks
  const int bz = id & 3, by = (id >> 2) & 3, bx = id >> 4;
  const int m0 = bx * 64;
  const int n0 = by * 64;
  const int k0 = bz * 320;
  float* dst = part + (size_t)bz * ((size_t)B_SZ * H_N);
  __shared__ unsigned short AhL[64 * LDSP], AlL[64 * LDSP];
  __shared__ unsigned short BhL[64 * LDSP];
  const int t = threadIdx.x;
  const int lane = t & 63;
  const int w = t >> 6;
  const int fr = lane & 15;
  const int fq = lane >> 4;
  f32x4 acc[4] = {};
  for (int it = 0; it < 5; ++it) {
    int kb = k0 + it * 64;
#pragma unroll
    for (int j = 0; j < 2; ++j) {
      int c = t + j * 256;
      int row = c >> 3, ko = (c & 7) * 8;
      size_t ga = (size_t)(m0 + row) * KPAD2 + kb + ko;
      size_t gb = (size_t)(n0 + row) * KPAD2 + kb + ko;
      *(short8*)&AhL[row * LDSP + ko] = *(const short8*)&Ah[ga];
      *(short8*)&AlL[row * LDSP + ko] = *(const short8*)&Al[ga];
      *(short8*)&BhL[row * LDSP + ko] = *(const short8*)&Bh[gb];
    }
    __syncthreads();
#pragma unroll
    for (int ks = 0; ks < 2; ++ks) {
      int aoff = (w * 16 + fr) * LDSP + fq * 8 + ks * 32;
      short8 ah = *(const short8*)&AhL[aoff];
      short8 al = *(const short8*)&AlL[aoff];
#pragma unroll
      for (int nt = 0; nt < 4; ++nt) {
        int boff = (nt * 16 + fr) * LDSP + fq * 8 + ks * 32;
        short8 bh = *(const short8*)&BhL[boff];
        acc[nt] = __builtin_amdgcn_mfma_f32_16x16x32_bf16(ah, bh, acc[nt], 0, 0, 0);
        acc[nt] = __builtin_amdgcn_mfma_f32_16x16x32_bf16(al, bh, acc[nt], 0, 0, 0);
      }
    }
    __syncthreads();
  }
  // C layout: col = lane&15, row = (lane>>4)*4 + reg  [m89-verified]
  int mrow = m0 + w * 16 + fq * 4;
#pragma unroll
  for (int nt = 0; nt < 4; ++nt) {
    int ncol = n0 + nt * 16 + fr;
#pragma unroll
    for (int r = 0; r < 4; ++r)
      dst[(size_t)(mrow + r) * H_N + ncol] = acc[nt][r];
  }
}

// ---------------------------------------------------------------------------
// Kernel 3: h1 = relu( relu(sum_z part_z + bb0) @ Wb1^T + bb1 ) via bf16
// MFMA; fused reduce+bias+relu+bf16 in A-staging. BM=64 BN=32, 4 waves.
// ---------------------------------------------------------------------------
#define LDSP2 72
__global__ __launch_bounds__(256) void k_gemm2b(const float* __restrict__ part,
                                                const float* __restrict__ bb0,
                                                const float* __restrict__ Bm,
                                                const float* __restrict__ bias,
                                                float* __restrict__ h1) {
  int flat = blockIdx.x + 32 * blockIdx.y;      // 0..255
  int id = (flat & 7) * 32 + (flat >> 3);       // XCD chunks, x slowest
  const int m0 = (id >> 3) * 64;
  const int n0 = (id & 7) * 32;
  const size_t BH = (size_t)B_SZ * H_N;
  __shared__ unsigned short AtL[64 * LDSP2];
  __shared__ unsigned short BtL[32 * LDSP2];
  const int t = threadIdx.x;
  const int lane = t & 63;
  const int w = t >> 6;
  const int fr = lane & 15;
  const int fq = lane >> 4;
  f32x4 acc[2] = {};
  for (int it = 0; it < 4; ++it) {
    int kb = it * 64;
#pragma unroll
    for (int j = 0; j < 4; ++j) {
      int g = t + j * 256;
      int row = g >> 4, c4 = g & 15;
      size_t base = (size_t)(m0 + row) * H_N + kb + c4 * 4;
      float4 v0 = *(const float4*)&part[base];
      float4 v1 = *(const float4*)&part[base + BH];
      float4 v2 = *(const float4*)&part[base + 2 * BH];
      float4 v3 = *(const float4*)&part[base + 3 * BH];
      float4 bi = *(const float4*)&bb0[kb + c4 * 4];
      ushort4 o;
      o.x = bf16_hi(fmaxf(v0.x + v1.x + v2.x + v3.x + bi.x, 0.f));
      o.y = bf16_hi(fmaxf(v0.y + v1.y + v2.y + v3.y + bi.y, 0.f));
      o.z = bf16_hi(fmaxf(v0.z + v1.z + v2.z + v3.z + bi.z, 0.f));
      o.w = bf16_hi(fmaxf(v0.w + v1.w + v2.w + v3.w + bi.w, 0.f));
      *(ushort4*)&AtL[row * LDSP2 + c4 * 4] = o;
    }
#pragma unroll
    for (int j = 0; j < 2; ++j) {
      int g = t + j * 256;
      int row = g >> 4, c4 = g & 15;
      float4 v = *(const float4*)&Bm[(size_t)(n0 + row) * H_N + kb + c4 * 4];
      ushort4 o;
      o.x = bf16_hi(v.x); o.y = bf16_hi(v.y);
      o.z = bf16_hi(v.z); o.w = bf16_hi(v.w);
      *(ushort4*)&BtL[row * LDSP2 + c4 * 4] = o;
    }
    __syncthreads();
#pragma unroll
    for (int ks = 0; ks < 2; ++ks) {
      short8 a8 = *(const short8*)&AtL[(w * 16 + fr) * LDSP2 + fq * 8 + ks * 32];
#pragma unroll
      for (int nt = 0; nt < 2; ++nt) {
        short8 b8 =
            *(const short8*)&BtL[(nt * 16 + fr) * LDSP2 + fq * 8 + ks * 32];
        acc[nt] = __builtin_amdgcn_mfma_f32_16x16x32_bf16(a8, b8, acc[nt], 0, 0, 0);
      }
    }
    __syncthreads();
  }
  int mrow = m0 + w * 16 + fq * 4;
#pragma unroll
  for (int nt = 0; nt < 2; ++nt) {
    int ncol = n0 + nt * 16 + fr;
    float bs = bias[ncol];
#pragma unroll
    for (int r = 0; r < 4; ++r)
      h1[(size_t)(mrow + r) * H_N + ncol] = fmaxf(acc[nt][r] + bs, 0.f);
  }
}

// ---------------------------------------------------------------------------
// Kernel 4: out[b,:] = h1[b,:] @ Wout^T + bout. One wave per batch row.
// ---------------------------------------------------------------------------
__global__ __launch_bounds__(256) void k_out(const float* __restrict__ h1,
                                             const float* __restrict__ Wout,
                                             const float* __restrict__ bout,
                                             float* __restrict__ out) {
  int w = threadIdx.x >> 6, lane = threadIdx.x & 63;
  int b = blockIdx.x * 4 + w;
  const float* hr = h1 + (size_t)b * H_N;
  float h[4];
#pragma unroll
  for (int j = 0; j < 4; ++j) h[j] = hr[lane + 64 * j];
  float acc[10];
#pragma unroll
  for (int o = 0; o < 10; ++o) {
    float s = 0.f;
#pragma unroll
    for (int j = 0; j < 4; ++j) s += h[j] * Wout[o * H_N + lane + 64 * j];
#pragma unroll
    for (int m = 32; m >= 1; m >>= 1) s += __shfl_xor(s, m);
    acc[o] = s;
  }
  if (lane == 0) {
#pragma unroll
    for (int o = 0; o < 10; ++o) out[(size_t)b * O_N + o] = acc[o] + bout[o];
  }
}

// ---------------------------------------------------------------------------
extern "C" void kernel_launch(void* const* d_in, const int* in_sizes, int n_in,
                              void* d_out, int out_size, void* d_ws,
                              size_t ws_size, hipStream_t stream) {
  (void)in_sizes; (void)n_in; (void)out_size; (void)ws_size;
  const float* x    = (const float*)d_in[0];
  const float* W    = (const float*)d_in[1];
  const float* bvec = (const float*)d_in[2];
  const float* Wb0  = (const float*)d_in[3];
  const float* bb0  = (const float*)d_in[4];
  const float* Wb1  = (const float*)d_in[5];
  const float* bb1  = (const float*)d_in[6];
  const float* Wout = (const float*)d_in[7];
  const float* bout = (const float*)d_in[8];

  float* out   = (float*)d_out;     // B*10
  float* masks = out + B_SZ * O_N;  // B*48

  char* wsb = (char*)d_ws;
  unsigned short* Ch = (unsigned short*)wsb;                // B*KPAD2 us
  unsigned short* Cl = Ch + (size_t)B_SZ * KPAD2;
  unsigned short* Gh = Cl + (size_t)B_SZ * KPAD2;           // H*KPAD2 us
  float* part = (float*)(Gh + (size_t)H_N * KPAD2);         // 4*B*H f32
  float* h1 = part + 4 * (size_t)B_SZ * H_N;                // B*H f32
  // total ~22 MB

  k1<<<dim3(704), 256, 0, stream>>>(W, Wb0, x, bvec, Gh, Ch, Cl, masks);
  k_gemm_bf16<<<dim3(32, 4, 4), 256, 0, stream>>>(Ch, Cl, Gh, part);
  k_gemm2b<<<dim3(32, 8), 256, 0, stream>>>(part, bb0, Wb1, bb1, h1);
  k_out<<<dim3(512), 256, 0, stream>>>(h1, Wout, bout, out);
}